// Round 20
// baseline (141.540 us; speedup 1.0000x reference)
//
#include <hip/hip_runtime.h>
#include <stdint.h>

typedef unsigned long long u64;
typedef unsigned int u32;
typedef unsigned short u16;

struct InPtrs { const float* p[37]; };

// workspace layout (bytes)
#define OFF_THR1     0        // double[16]
#define OFF_W1D      128      // double[144]
#define OFF_WREC     1280     // u64[32*12]  per-ch: wc0..6, wb0..2, pad, pad (96B stride)
#define OFF_SMAXBC   4352     // u64[825]    25 classes x stride 33: (wam<<48)|(pA<<32)|(pB<<16)|pC
#define OFF_SMAXF1   11008    // i32[1024]   (SmaxF1+1)
#define OFF_WF2P     15104    // u64[160]
#define OFF_A2       16384    // float[10]
#define OFF_C2       16448    // float[10]
#define OFF_WF1P     16512    // u64[1024*74]
#define OFF_H2       622720   // u32[B*148] == u64[B*74]
#define OFF_HB2      3047552  // u64[B*16]

__device__ __forceinline__ int clampi(int v, int lo, int hi) { return v < lo ? lo : (v > hi ? hi : v); }

// ---------------------------------------------------------------- W0: packs + tables, 4 independent blocks
__global__ __launch_bounds__(1024) void kprep(InPtrs P, char* __restrict__ ws) {
  const float* w1 = P.p[1]; const float* b1 = P.p[2];
  const float* g1 = P.p[3]; const float* bt1 = P.p[4]; const float* m1 = P.p[5]; const float* v1 = P.p[6];
  const float* wa = P.p[7]; const float* ba = P.p[8];
  const float* ag = P.p[9]; const float* abt = P.p[10]; const float* am = P.p[11]; const float* av = P.p[12];
  const float* wb = P.p[13]; const float* bb = P.p[14];
  const float* bg = P.p[15]; const float* bbt = P.p[16]; const float* bm = P.p[17]; const float* bv = P.p[18];
  const float* wc = P.p[19]; const float* bc = P.p[20];
  const float* bf1 = P.p[26];
  const float* f1g = P.p[27]; const float* f1bt = P.p[28]; const float* f1m = P.p[29]; const float* f1v = P.p[30];
  const float* wf2 = P.p[31]; const float* bf2 = P.p[32];
  const float* cg = P.p[21]; const float* cbt = P.p[22]; const float* cm = P.p[23]; const float* cv = P.p[24];
  const float* f2g = P.p[33]; const float* f2bt = P.p[34]; const float* f2m = P.p[35]; const float* f2v = P.p[36];

  double* thr1 = (double*)(ws + OFF_THR1);
  double* w1d  = (double*)(ws + OFF_W1D);
  u64* wrec = (u64*)(ws + OFF_WREC);
  u64* smaxbc = (u64*)(ws + OFF_SMAXBC);
  int* smf1 = (int*)(ws + OFF_SMAXF1);
  u64* wf2p = (u64*)(ws + OFF_WF2P);
  float* a2 = (float*)(ws + OFF_A2);
  float* c2 = (float*)(ws + OFF_C2);

  __shared__ u64 wbpL[96];
  __shared__ u64 wcpL[256];
  __shared__ double thBL[32], thCL[32];
  __shared__ u32 wamS[32], smaS[32];

  int t = threadIdx.x;
  int wave = t >> 6, lane = t & 63;
  int blk = blockIdx.x;

  if (blk == 0) {
    if (t < 32) {
      u32 m = 0;
      for (int c = 0; c < 16; c++) if (wa[t*16+c] >= 0.f) m |= 1u << c;
      wamS[t] = m;
      double ia = (double)ag[t] / sqrt((double)av[t] + 1e-5);
      double thA = (double)am[t] - (double)abt[t]/ia - (double)ba[t];
      int kmin = (int)ceil(thA);
      int sm = (16 - kmin) >> 1;
      smaS[t] = (u32)clampi(sm + 1, 0, 65535);
      double ib = (double)bg[t] / sqrt((double)bv[t] + 1e-5);
      thBL[t] = (double)bm[t] - (double)bbt[t]/ib - (double)bb[t];
      double ic = (double)cg[t] / sqrt((double)cv[t] + 1e-5);
      thCL[t] = (double)cm[t] - (double)cbt[t]/ic - (double)bc[t];
    }
    for (int w = wave; w < 96; w += 16) {
      int ch = w / 3, k = w - 3*ch;
      int tt = 4*k + (lane >> 4), c = lane & 15;
      bool pred = false;
      if (tt < 9) pred = (wb[ch*144 + c*9 + tt] >= 0.f);
      u64 m = __ballot(pred);
      if (lane == 0) wbpL[w] = m;
    }
    for (int w = wave; w < 256; w += 16) {
      int ch = w >> 3, k = w & 7;
      int tt = 4*k + (lane >> 4), c = lane & 15;
      bool pred = false;
      if (k < 7 && tt < 25) pred = (wc[ch*400 + c*25 + tt] >= 0.f);
      u64 m = __ballot(pred);
      if (lane == 0) wcpL[w] = m;
    }
    __syncthreads();
    if (t < 384) {
      int ch = t / 12, k = t - 12*ch;
      u64 v = 0;
      if (k < 7) v = wcpL[ch*8 + k];
      else if (k < 10) v = wbpL[ch*3 + (k - 7)];
      wrec[ch*12 + k] = v;
    }
    if (t < 800) {
      const int irep[5] = {0, 1, 5, 12, 13};
      int cls = t >> 5, ch = t & 31;
      int rc = cls / 5, cc = cls - 5*rc;
      int ir = irep[rc], jr = irep[cc];
      u64 invC[7] = {0,0,0,0,0,0,0};
      u64 invB[3] = {0,0,0};
      int nInvC = 0, nInvB = 0;
      #pragma unroll
      for (int tt = 0; tt < 25; tt++) {
        int di = tt/5 - 2, dj = tt%5 - 2;
        bool val = (ir+di >= 0 && ir+di < 14 && jr+dj >= 0 && jr+dj < 14);
        if (!val) { invC[tt>>2] |= 0xFFFFull << ((tt&3)*16); nInvC++; }
      }
      #pragma unroll
      for (int tt = 0; tt < 9; tt++) {
        int di = tt/3 - 1, dj = tt%3 - 1;
        bool val = (ir+di >= 0 && ir+di < 14 && jr+dj >= 0 && jr+dj < 14);
        if (!val) { invB[tt>>2] |= 0xFFFFull << ((tt&3)*16); nInvB++; }
      }
      int pinvC = 0;
      #pragma unroll
      for (int k = 0; k < 7; k++) pinvC += __popcll(wcpL[ch*8+k] & invC[k]);
      int pinvB = 0;
      #pragma unroll
      for (int k = 0; k < 3; k++) pinvB += __popcll(wbpL[ch*3+k] & invB[k]);
      int nvC = 16*(25 - nInvC), nvB = 16*(9 - nInvB);
      int kminC = (int)ceil(thCL[ch]);
      int kminB = (int)ceil(thBL[ch]);
      int smC = ((nvC - kminC) >> 1) + pinvC;
      int smB = ((nvB - kminB) >> 1) + pinvB;
      u64 pB = (u64)clampi(smB + 1, 0, 65535);
      u64 pC = (u64)clampi(smC + 1, 0, 65535);
      smaxbc[cls*33 + ch] = ((u64)wamS[ch] << 48) | ((u64)smaS[ch] << 32) | (pB << 16) | pC;
    }
  } else if (blk == 1) {
    for (int w = wave; w < 160; w += 16) {
      int o = w >> 4, kk = w & 15;
      bool pred = (wf2[o*1024 + kk*64 + lane] >= 0.f);
      u64 m = __ballot(pred);
      if (lane == 0) wf2p[w] = m;
    }
  } else if (blk == 2) {
    {
      int o = t;
      double inv = (double)f1g[o] / sqrt((double)f1v[o] + 1e-5);
      double th = (double)f1m[o] - (double)f1bt[o]/inv - (double)bf1[o];
      int kmin = (int)ceil(th);
      smf1[o] = ((4704 - kmin) >> 1) + 1;
    }
    if (t < 10) {
      double inv = (double)f2g[t] / sqrt((double)f2v[t] + 1e-5);
      a2[t] = (float)inv;
      c2[t] = (float)(((double)bf2[t] - (double)f2m[t]) * inv + (double)f2bt[t]);
    }
  } else {
    if (t < 144) w1d[t] = (w1[t] >= 0.f) ? 1.0 : -1.0;
    if (t < 16) {
      double inv = (double)g1[t] / sqrt((double)v1[t] + 1e-5);
      thr1[t] = (double)m1[t] - (double)bt1[t] / inv - (double)b1[t];
    }
  }
}

// ---------------------------------------------------------------- A+B fused + wf1 pack merged (grid = 1024 + B)
__global__ __launch_bounds__(256) void kfused(const float* __restrict__ x, const float* __restrict__ wf1,
                                              const char* __restrict__ ws,
                                              u32* __restrict__ h2u32, u64* __restrict__ wf1p) {
  __shared__ float wshF[144];
  __shared__ float thrF[16];
  __shared__ double thrD[16];
  __shared__ u16 hp[324];          // 18x18 zero-padded
  __shared__ u32 rr[196][3];
  __shared__ u64 smbc[825];
  __shared__ __align__(16) u64 wrecL[384];  // 32 ch x 12 u64 (96B records)

  int t = threadIdx.x;

  // ---------------- pack path (blocks 0..1023), flag aliases smbc (6600B >= 4704B)
  if (blockIdx.x < 1024) {
    unsigned char* flag = (unsigned char*)smbc;
    int o = blockIdx.x;
    const float* row = wf1 + (size_t)o*4704;
    for (int i = t; i < 4704; i += 256) flag[i] = (row[i] >= 0.f);   // f-order: f = c*49+s
    __syncthreads();
    int w0 = t >> 6, lane = t & 63;      // 4 waves
    for (int w = w0; w < 74; w += 4) {
      int fp = w*64 + lane;
      bool bit = false;
      if (fp < 4704) { int s = fp / 96, c = fp - 96*s; bit = flag[c*49 + s] != 0; }
      u64 m = __ballot(bit);
      if (lane == 0) wf1p[(size_t)o*74 + w] = m;
    }
    return;
  }

  // ---------------- fused path
  int b = blockIdx.x - 1024;
  const double* w1d  = (const double*)(ws + OFF_W1D);
  const double* thr1 = (const double*)(ws + OFF_THR1);
  const u64* wrec_g = (const u64*)(ws + OFF_WREC);
  const u64* smaxbc_g = (const u64*)(ws + OFF_SMAXBC);

  if (t < 144) wshF[t] = (float)w1d[t];                 // exact (+/-1)
  else if (t < 160) { thrF[t-144] = (float)thr1[t-144]; thrD[t-144] = thr1[t-144]; }
  for (int i = t; i < 384; i += 256) wrecL[i] = wrec_g[i];
  for (int i = t; i < 825; i += 256) smbc[i] = smaxbc_g[i];
  {
    u32* hp32 = (u32*)hp;
    for (int i = t; i < 162; i += 256) hp32[i] = 0;
  }
  __syncthreads();

  int pi = t / 14, pj = t - 14*pi;              // valid for t < 196
  // ---- stem: f32 conv + max-guard (f64 recompute near threshold -> bit-identical decisions)
  if (t < 196) {
    const float* xi = x + (size_t)b*784;
    float p[16];
    #pragma unroll
    for (int r = 0; r < 4; r++) {
      int ii = 2*pi - 1 + r;
      #pragma unroll
      for (int c = 0; c < 4; c++) {
        int jj = 2*pj - 1 + c;
        bool v = (ii >= 0 && ii < 28 && jj >= 0 && jj < 28);
        int a = v ? (ii*28 + jj) : 0;
        float f = xi[a];
        p[r*4+c] = v ? f : 0.0f;
      }
    }
    u32 bits = 0;
    for (int o = 0; o < 16; o++) {
      float a00 = 0.f, a01 = 0.f, a10 = 0.f, a11 = 0.f;
      #pragma unroll
      for (int dy = 0; dy < 3; dy++)
        #pragma unroll
        for (int dx = 0; dx < 3; dx++) {
          float w = wshF[o*9 + dy*3 + dx];
          a00 += p[dy*4 + dx]       * w;
          a01 += p[dy*4 + dx + 1]   * w;
          a10 += p[(dy+1)*4 + dx]   * w;
          a11 += p[(dy+1)*4 + dx+1] * w;
        }
      float th = thrF[o];
      float mx = fmaxf(fmaxf(a00, a01), fmaxf(a10, a11));
      bool bit;
      if (fabsf(mx - th) < 5e-4f) {
        double d00 = 0.0, d01 = 0.0, d10 = 0.0, d11 = 0.0;
        #pragma unroll
        for (int dy = 0; dy < 3; dy++)
          #pragma unroll
          for (int dx = 0; dx < 3; dx++) {
            double w = (double)wshF[o*9 + dy*3 + dx];
            d00 += (double)p[dy*4 + dx]       * w;
            d01 += (double)p[dy*4 + dx + 1]   * w;
            d10 += (double)p[(dy+1)*4 + dx]   * w;
            d11 += (double)p[(dy+1)*4 + dx+1] * w;
          }
        double thd = thrD[o];
        bit = (d00 >= thd) || (d01 >= thd) || (d10 >= thd) || (d11 >= thd);
      } else {
        bit = (mx >= th);
      }
      bits |= (u32)bit << o;
    }
    hp[(pi+2)*18 + (pj+2)] = (u16)bits;
  }
  __syncthreads();

  // ---- branches: gather 5x5 taps from zero-padded tile
  if (t < 196) {
    const u16* hpb = &hp[pi*18 + pj];
    u32 tp[25];
    #pragma unroll
    for (int r = 0; r < 5; r++)
      #pragma unroll
      for (int c = 0; c < 5; c++) tp[r*5+c] = hpb[r*18 + c];
    u32 h0 = tp[12];
    u64 qc[6], qb[2];
    u32 qc6 = tp[24], qb2 = tp[18];
    qc[0] = (u64)tp[0]  | (u64)tp[1]<<16  | (u64)tp[2]<<32  | (u64)tp[3]<<48;
    qc[1] = (u64)tp[4]  | (u64)tp[5]<<16  | (u64)tp[6]<<32  | (u64)tp[7]<<48;
    qc[2] = (u64)tp[8]  | (u64)tp[9]<<16  | (u64)tp[10]<<32 | (u64)tp[11]<<48;
    qc[3] = (u64)tp[12] | (u64)tp[13]<<16 | (u64)tp[14]<<32 | (u64)tp[15]<<48;
    qc[4] = (u64)tp[16] | (u64)tp[17]<<16 | (u64)tp[18]<<32 | (u64)tp[19]<<48;
    qc[5] = (u64)tp[20] | (u64)tp[21]<<16 | (u64)tp[22]<<32 | (u64)tp[23]<<48;
    qb[0] = (u64)tp[6]  | (u64)tp[7]<<16  | (u64)tp[8]<<32  | (u64)tp[11]<<48;
    qb[1] = (u64)tp[12] | (u64)tp[13]<<16 | (u64)tp[16]<<32 | (u64)tp[17]<<48;
    int rc = (pi < 2) ? pi : (pi > 11 ? pi - 9 : 2);
    int cc = (pj < 2) ? pj : (pj > 11 ? pj - 9 : 2);
    const u64* mrow = &smbc[(rc*5 + cc)*33];
    const ulonglong2* R2 = (const ulonglong2*)wrecL;
    u32 r0 = 0, r1 = 0, r2 = 0;
    #pragma unroll 8
    for (int ch = 0; ch < 32; ch++) {
      ulonglong2 w01 = R2[ch*6+0], w23 = R2[ch*6+1], w45 = R2[ch*6+2];
      ulonglong2 w67 = R2[ch*6+3], w89 = R2[ch*6+4];
      u64 meta = mrow[ch];
      int Sc = __popcll(qc[0]^w01.x) + __popcll(qc[1]^w01.y) + __popcll(qc[2]^w23.x)
             + __popcll(qc[3]^w23.y) + __popcll(qc[4]^w45.x) + __popcll(qc[5]^w45.y)
             + __popc(qc6 ^ (u32)w67.x);
      int Sb = __popcll(qb[0]^w67.y) + __popcll(qb[1]^w89.x) + __popc(qb2 ^ (u32)w89.y);
      int Sa = __popc(h0 ^ (u32)(meta >> 48));
      r0 |= (u32)(Sa < (int)((meta >> 32) & 0xFFFFu)) << ch;
      r1 |= (u32)(Sb < (int)((meta >> 16) & 0xFFFFu)) << ch;
      r2 |= (u32)(Sc < (int)(meta & 0xFFFFu)) << ch;
    }
    rr[t][0] = r0; rr[t][1] = r1; rr[t][2] = r2;
  }
  __syncthreads();
  // pool 2x2 (OR) and store directly: 148 u32, f' = s*96 + c order
  if (t < 148) {
    u32 v = 0;
    if (t < 147) {
      int s = t / 3, qq = t - 3*s;
      int sp = s / 7, sj = s - 7*sp;
      int base = (2*sp)*14 + 2*sj;
      v = rr[base][qq] | rr[base+1][qq] | rr[base+14][qq] | rr[base+15][qq];
    }
    h2u32[(size_t)b*148 + t] = v;
  }
}

// ---------------------------------------------------------------- C: FC1 XNOR-GEMM v2 (64img x 64out)
// wave = 64 lanes = 64 imgs; each wave owns 16 outs -> W reads wave-uniform (scalar path).
// A transposed in LDS aT[w][65-pad]; register-cached in halves (37 u64); cross-half sums in LDS.
__global__ __launch_bounds__(256) void kfc1(const u64* __restrict__ h2, const u64* __restrict__ wf1p,
                                            const int* __restrict__ smf1, u64* __restrict__ hb2) {
  __shared__ __align__(16) u64 aT[74*65];        // 38480 B, index w*65+img
  __shared__ u16 sums[64][66];                   // 8448 B, [img][out]
  __shared__ unsigned char bitsb[64][64];        // 4096 B
  int bx = blockIdx.x, by = blockIdx.y, t = threadIdx.x;
  // stage A transposed (global coalesced; LDS write ~4-way)
  const u64* ga = h2 + (size_t)by*64*74;
  for (int i = t; i < 64*74; i += 256) {
    int img = i / 74, w = i - 74*img;
    aT[w*65 + img] = ga[i];
  }
  __syncthreads();
  int lane = t & 63;
  int wv = __builtin_amdgcn_readfirstlane(t >> 6);
  u64 areg[37];
  // ---- half 0: words 0..36
  #pragma unroll
  for (int j = 0; j < 37; j++) areg[j] = aT[j*65 + lane];
  for (int oq = 0; oq < 4; oq++) {
    int ob = (wv << 4) + oq*4;
    const u64* W0 = wf1p + (size_t)(bx*64 + ob + 0)*74;
    const u64* W1 = wf1p + (size_t)(bx*64 + ob + 1)*74;
    const u64* W2 = wf1p + (size_t)(bx*64 + ob + 2)*74;
    const u64* W3 = wf1p + (size_t)(bx*64 + ob + 3)*74;
    int S0 = 0, S1 = 0, S2 = 0, S3 = 0;
    #pragma unroll
    for (int j = 0; j < 37; j++) {
      u64 a = areg[j];
      S0 += __popcll(a ^ W0[j]); S1 += __popcll(a ^ W1[j]);
      S2 += __popcll(a ^ W2[j]); S3 += __popcll(a ^ W3[j]);
    }
    sums[lane][ob+0] = (u16)S0; sums[lane][ob+1] = (u16)S1;
    sums[lane][ob+2] = (u16)S2; sums[lane][ob+3] = (u16)S3;
  }
  // ---- half 1: words 37..73
  #pragma unroll
  for (int j = 0; j < 37; j++) areg[j] = aT[(37 + j)*65 + lane];
  for (int oq = 0; oq < 4; oq++) {
    int ob = (wv << 4) + oq*4;
    const u64* W0 = wf1p + (size_t)(bx*64 + ob + 0)*74 + 37;
    const u64* W1 = wf1p + (size_t)(bx*64 + ob + 1)*74 + 37;
    const u64* W2 = wf1p + (size_t)(bx*64 + ob + 2)*74 + 37;
    const u64* W3 = wf1p + (size_t)(bx*64 + ob + 3)*74 + 37;
    int S0 = sums[lane][ob+0], S1 = sums[lane][ob+1];
    int S2 = sums[lane][ob+2], S3 = sums[lane][ob+3];
    #pragma unroll
    for (int j = 0; j < 37; j++) {
      u64 a = areg[j];
      S0 += __popcll(a ^ W0[j]); S1 += __popcll(a ^ W1[j]);
      S2 += __popcll(a ^ W2[j]); S3 += __popcll(a ^ W3[j]);
    }
    int th0 = smf1[bx*64 + ob + 0];
    int th1 = smf1[bx*64 + ob + 1];
    int th2 = smf1[bx*64 + ob + 2];
    int th3 = smf1[bx*64 + ob + 3];
    bitsb[lane][ob+0] = S0 < th0;
    bitsb[lane][ob+1] = S1 < th1;
    bitsb[lane][ob+2] = S2 < th2;
    bitsb[lane][ob+3] = S3 < th3;
  }
  __syncthreads();
  if (t < 64) {
    u64 wd = 0;
    #pragma unroll
    for (int j = 0; j < 64; j++) wd |= (u64)bitsb[t][j] << j;
    hb2[(size_t)(by*64 + t)*16 + bx] = wd;
  }
}

// ---------------------------------------------------------------- D: FC2 + BN + log_softmax
__global__ __launch_bounds__(256) void kfc2(const u64* __restrict__ hb2, const char* __restrict__ ws,
                                            float* __restrict__ out, int B) {
  __shared__ u64 w2[160];
  __shared__ float a2s[10], c2s[10];
  const u64* wf2p = (const u64*)(ws + OFF_WF2P);
  const float* a2 = (const float*)(ws + OFF_A2);
  const float* c2 = (const float*)(ws + OFF_C2);
  int t = threadIdx.x;
  for (int i = t; i < 160; i += 256) w2[i] = wf2p[i];
  if (t < 10) { a2s[t] = a2[t]; c2s[t] = c2[t]; }
  __syncthreads();
  int img = blockIdx.x*256 + t;
  if (img >= B) return;
  u64 a[16];
  #pragma unroll
  for (int w = 0; w < 16; w++) a[w] = hb2[(size_t)img*16 + w];
  float z[10];
  #pragma unroll
  for (int o = 0; o < 10; o++) {
    int S = 0;
    #pragma unroll
    for (int w = 0; w < 16; w++) S += __popcll(a[w] ^ w2[o*16 + w]);
    z[o] = (float)(1024 - 2*S) * a2s[o] + c2s[o];
  }
  float M = z[0];
  #pragma unroll
  for (int o = 1; o < 10; o++) M = fmaxf(M, z[o]);
  float se = 0.f;
  #pragma unroll
  for (int o = 0; o < 10; o++) se += expf(z[o] - M);
  float lse = M + logf(se);
  #pragma unroll
  for (int o = 0; o < 10; o++) out[(size_t)img*10 + o] = z[o] - lse;
}

// ----------------------------------------------------------------
extern "C" void kernel_launch(void* const* d_in, const int* in_sizes, int n_in,
                              void* d_out, int out_size, void* d_ws, size_t ws_size,
                              hipStream_t stream) {
  int B = in_sizes[0] / 784;   // 4096
  char* ws = (char*)d_ws;
  InPtrs P;
  for (int i = 0; i < 37; i++) P.p[i] = (const float*)d_in[i];

  kprep<<<4, 1024, 0, stream>>>(P, ws);
  kfused<<<1024 + B, 256, 0, stream>>>((const float*)d_in[0], (const float*)d_in[25], ws,
                                       (u32*)(ws + OFF_H2), (u64*)(ws + OFF_WF1P));
  dim3 g(16, B/64);
  kfc1<<<g, 256, 0, stream>>>((const u64*)(ws + OFF_H2), (const u64*)(ws + OFF_WF1P),
                              (const int*)(ws + OFF_SMAXF1), (u64*)(ws + OFF_HB2));
  kfc2<<<(B + 255)/256, 256, 0, stream>>>((const u64*)(ws + OFF_HB2), ws, (float*)d_out, B);
}

// Round 21
// 138.662 us; speedup vs baseline: 1.0208x; 1.0208x over previous
//
#include <hip/hip_runtime.h>
#include <stdint.h>

typedef unsigned long long u64;
typedef unsigned int u32;
typedef unsigned short u16;

struct InPtrs { const float* p[37]; };

// workspace layout (bytes)
#define OFF_THR1     0        // double[16]
#define OFF_W1D      128      // double[144]
#define OFF_WREC     1280     // u64[32*12]  per-ch: wc0..6, wb0..2, pad, pad (96B stride)
#define OFF_SMAXBC   4352     // u64[825]    25 classes x stride 33: (wam<<48)|(pA<<32)|(pB<<16)|pC
#define OFF_SMAXF1   11008    // i32[1024]   (SmaxF1+1)
#define OFF_WF2P     15104    // u64[160]
#define OFF_A2       16384    // float[10]
#define OFF_C2       16448    // float[10]
#define OFF_WF1P     16512    // u64[1024*74]
#define OFF_H2       622720   // u32[B*148] == u64[B*74]
#define OFF_HB2      3047552  // u64[B*16]

__device__ __forceinline__ int clampi(int v, int lo, int hi) { return v < lo ? lo : (v > hi ? hi : v); }

// ---------------------------------------------------------------- W0: packs + tables, 4 independent blocks
__global__ __launch_bounds__(1024) void kprep(InPtrs P, char* __restrict__ ws) {
  const float* w1 = P.p[1]; const float* b1 = P.p[2];
  const float* g1 = P.p[3]; const float* bt1 = P.p[4]; const float* m1 = P.p[5]; const float* v1 = P.p[6];
  const float* wa = P.p[7]; const float* ba = P.p[8];
  const float* ag = P.p[9]; const float* abt = P.p[10]; const float* am = P.p[11]; const float* av = P.p[12];
  const float* wb = P.p[13]; const float* bb = P.p[14];
  const float* bg = P.p[15]; const float* bbt = P.p[16]; const float* bm = P.p[17]; const float* bv = P.p[18];
  const float* wc = P.p[19]; const float* bc = P.p[20];
  const float* bf1 = P.p[26];
  const float* f1g = P.p[27]; const float* f1bt = P.p[28]; const float* f1m = P.p[29]; const float* f1v = P.p[30];
  const float* wf2 = P.p[31]; const float* bf2 = P.p[32];
  const float* cg = P.p[21]; const float* cbt = P.p[22]; const float* cm = P.p[23]; const float* cv = P.p[24];
  const float* f2g = P.p[33]; const float* f2bt = P.p[34]; const float* f2m = P.p[35]; const float* f2v = P.p[36];

  double* thr1 = (double*)(ws + OFF_THR1);
  double* w1d  = (double*)(ws + OFF_W1D);
  u64* wrec = (u64*)(ws + OFF_WREC);
  u64* smaxbc = (u64*)(ws + OFF_SMAXBC);
  int* smf1 = (int*)(ws + OFF_SMAXF1);
  u64* wf2p = (u64*)(ws + OFF_WF2P);
  float* a2 = (float*)(ws + OFF_A2);
  float* c2 = (float*)(ws + OFF_C2);

  __shared__ u64 wbpL[96];
  __shared__ u64 wcpL[256];
  __shared__ double thBL[32], thCL[32];
  __shared__ u32 wamS[32], smaS[32];

  int t = threadIdx.x;
  int wave = t >> 6, lane = t & 63;
  int blk = blockIdx.x;

  if (blk == 0) {
    if (t < 32) {
      u32 m = 0;
      for (int c = 0; c < 16; c++) if (wa[t*16+c] >= 0.f) m |= 1u << c;
      wamS[t] = m;
      double ia = (double)ag[t] / sqrt((double)av[t] + 1e-5);
      double thA = (double)am[t] - (double)abt[t]/ia - (double)ba[t];
      int kmin = (int)ceil(thA);
      int sm = (16 - kmin) >> 1;
      smaS[t] = (u32)clampi(sm + 1, 0, 65535);
      double ib = (double)bg[t] / sqrt((double)bv[t] + 1e-5);
      thBL[t] = (double)bm[t] - (double)bbt[t]/ib - (double)bb[t];
      double ic = (double)cg[t] / sqrt((double)cv[t] + 1e-5);
      thCL[t] = (double)cm[t] - (double)cbt[t]/ic - (double)bc[t];
    }
    for (int w = wave; w < 96; w += 16) {
      int ch = w / 3, k = w - 3*ch;
      int tt = 4*k + (lane >> 4), c = lane & 15;
      bool pred = false;
      if (tt < 9) pred = (wb[ch*144 + c*9 + tt] >= 0.f);
      u64 m = __ballot(pred);
      if (lane == 0) wbpL[w] = m;
    }
    for (int w = wave; w < 256; w += 16) {
      int ch = w >> 3, k = w & 7;
      int tt = 4*k + (lane >> 4), c = lane & 15;
      bool pred = false;
      if (k < 7 && tt < 25) pred = (wc[ch*400 + c*25 + tt] >= 0.f);
      u64 m = __ballot(pred);
      if (lane == 0) wcpL[w] = m;
    }
    __syncthreads();
    if (t < 384) {
      int ch = t / 12, k = t - 12*ch;
      u64 v = 0;
      if (k < 7) v = wcpL[ch*8 + k];
      else if (k < 10) v = wbpL[ch*3 + (k - 7)];
      wrec[ch*12 + k] = v;
    }
    if (t < 800) {
      const int irep[5] = {0, 1, 5, 12, 13};
      int cls = t >> 5, ch = t & 31;
      int rc = cls / 5, cc = cls - 5*rc;
      int ir = irep[rc], jr = irep[cc];
      u64 invC[7] = {0,0,0,0,0,0,0};
      u64 invB[3] = {0,0,0};
      int nInvC = 0, nInvB = 0;
      #pragma unroll
      for (int tt = 0; tt < 25; tt++) {
        int di = tt/5 - 2, dj = tt%5 - 2;
        bool val = (ir+di >= 0 && ir+di < 14 && jr+dj >= 0 && jr+dj < 14);
        if (!val) { invC[tt>>2] |= 0xFFFFull << ((tt&3)*16); nInvC++; }
      }
      #pragma unroll
      for (int tt = 0; tt < 9; tt++) {
        int di = tt/3 - 1, dj = tt%3 - 1;
        bool val = (ir+di >= 0 && ir+di < 14 && jr+dj >= 0 && jr+dj < 14);
        if (!val) { invB[tt>>2] |= 0xFFFFull << ((tt&3)*16); nInvB++; }
      }
      int pinvC = 0;
      #pragma unroll
      for (int k = 0; k < 7; k++) pinvC += __popcll(wcpL[ch*8+k] & invC[k]);
      int pinvB = 0;
      #pragma unroll
      for (int k = 0; k < 3; k++) pinvB += __popcll(wbpL[ch*3+k] & invB[k]);
      int nvC = 16*(25 - nInvC), nvB = 16*(9 - nInvB);
      int kminC = (int)ceil(thCL[ch]);
      int kminB = (int)ceil(thBL[ch]);
      int smC = ((nvC - kminC) >> 1) + pinvC;
      int smB = ((nvB - kminB) >> 1) + pinvB;
      u64 pB = (u64)clampi(smB + 1, 0, 65535);
      u64 pC = (u64)clampi(smC + 1, 0, 65535);
      smaxbc[cls*33 + ch] = ((u64)wamS[ch] << 48) | ((u64)smaS[ch] << 32) | (pB << 16) | pC;
    }
  } else if (blk == 1) {
    for (int w = wave; w < 160; w += 16) {
      int o = w >> 4, kk = w & 15;
      bool pred = (wf2[o*1024 + kk*64 + lane] >= 0.f);
      u64 m = __ballot(pred);
      if (lane == 0) wf2p[w] = m;
    }
  } else if (blk == 2) {
    {
      int o = t;
      double inv = (double)f1g[o] / sqrt((double)f1v[o] + 1e-5);
      double th = (double)f1m[o] - (double)f1bt[o]/inv - (double)bf1[o];
      int kmin = (int)ceil(th);
      smf1[o] = ((4704 - kmin) >> 1) + 1;
    }
    if (t < 10) {
      double inv = (double)f2g[t] / sqrt((double)f2v[t] + 1e-5);
      a2[t] = (float)inv;
      c2[t] = (float)(((double)bf2[t] - (double)f2m[t]) * inv + (double)f2bt[t]);
    }
  } else {
    if (t < 144) w1d[t] = (w1[t] >= 0.f) ? 1.0 : -1.0;
    if (t < 16) {
      double inv = (double)g1[t] / sqrt((double)v1[t] + 1e-5);
      thr1[t] = (double)m1[t] - (double)bt1[t] / inv - (double)b1[t];
    }
  }
}

// ---------------------------------------------------------------- A+B fused + wf1 pack merged (grid = 1024 + B)
// blocks 0..1023: pack one wf1 row (coalesced read, LDS permute to f' = s*96+c)
// blocks 1024..1023+B: fused stem+branch+pool (one image / 256 threads)
__global__ __launch_bounds__(256) void kfused(const float* __restrict__ x, const float* __restrict__ wf1,
                                              const char* __restrict__ ws,
                                              u32* __restrict__ h2u32, u64* __restrict__ wf1p) {
  __shared__ float wshF[144];
  __shared__ float thrF[16];
  __shared__ double thrD[16];
  __shared__ u16 hp[324];          // 18x18 zero-padded
  __shared__ u32 rr[196][3];
  __shared__ u64 smbc[825];
  __shared__ __align__(16) u64 wrecL[384];  // 32 ch x 12 u64 (96B records)

  int t = threadIdx.x;

  // ---------------- pack path (blocks 0..1023), flag aliases smbc (6600B >= 4704B)
  if (blockIdx.x < 1024) {
    unsigned char* flag = (unsigned char*)smbc;
    int o = blockIdx.x;
    const float* row = wf1 + (size_t)o*4704;
    for (int i = t; i < 4704; i += 256) flag[i] = (row[i] >= 0.f);   // f-order: f = c*49+s
    __syncthreads();
    int w0 = t >> 6, lane = t & 63;      // 4 waves
    for (int w = w0; w < 74; w += 4) {
      int fp = w*64 + lane;
      bool bit = false;
      if (fp < 4704) { int s = fp / 96, c = fp - 96*s; bit = flag[c*49 + s] != 0; }
      u64 m = __ballot(bit);
      if (lane == 0) wf1p[(size_t)o*74 + w] = m;
    }
    return;
  }

  // ---------------- fused path
  int b = blockIdx.x - 1024;
  const double* w1d  = (const double*)(ws + OFF_W1D);
  const double* thr1 = (const double*)(ws + OFF_THR1);
  const u64* wrec_g = (const u64*)(ws + OFF_WREC);
  const u64* smaxbc_g = (const u64*)(ws + OFF_SMAXBC);

  if (t < 144) wshF[t] = (float)w1d[t];                 // exact (+/-1)
  else if (t < 160) { thrF[t-144] = (float)thr1[t-144]; thrD[t-144] = thr1[t-144]; }
  for (int i = t; i < 384; i += 256) wrecL[i] = wrec_g[i];
  for (int i = t; i < 825; i += 256) smbc[i] = smaxbc_g[i];
  {
    u32* hp32 = (u32*)hp;
    for (int i = t; i < 162; i += 256) hp32[i] = 0;
  }
  __syncthreads();

  int pi = t / 14, pj = t - 14*pi;              // valid for t < 196
  // ---- stem: f32 conv + max-guard (f64 recompute near threshold -> bit-identical decisions)
  if (t < 196) {
    const float* xi = x + (size_t)b*784;
    float p[16];
    #pragma unroll
    for (int r = 0; r < 4; r++) {
      int ii = 2*pi - 1 + r;
      #pragma unroll
      for (int c = 0; c < 4; c++) {
        int jj = 2*pj - 1 + c;
        bool v = (ii >= 0 && ii < 28 && jj >= 0 && jj < 28);
        int a = v ? (ii*28 + jj) : 0;
        float f = xi[a];
        p[r*4+c] = v ? f : 0.0f;
      }
    }
    u32 bits = 0;
    for (int o = 0; o < 16; o++) {
      float a00 = 0.f, a01 = 0.f, a10 = 0.f, a11 = 0.f;
      #pragma unroll
      for (int dy = 0; dy < 3; dy++)
        #pragma unroll
        for (int dx = 0; dx < 3; dx++) {
          float w = wshF[o*9 + dy*3 + dx];
          a00 += p[dy*4 + dx]       * w;
          a01 += p[dy*4 + dx + 1]   * w;
          a10 += p[(dy+1)*4 + dx]   * w;
          a11 += p[(dy+1)*4 + dx+1] * w;
        }
      float th = thrF[o];
      float mx = fmaxf(fmaxf(a00, a01), fmaxf(a10, a11));
      bool bit;
      if (fabsf(mx - th) < 5e-4f) {
        double d00 = 0.0, d01 = 0.0, d10 = 0.0, d11 = 0.0;
        #pragma unroll
        for (int dy = 0; dy < 3; dy++)
          #pragma unroll
          for (int dx = 0; dx < 3; dx++) {
            double w = (double)wshF[o*9 + dy*3 + dx];
            d00 += (double)p[dy*4 + dx]       * w;
            d01 += (double)p[dy*4 + dx + 1]   * w;
            d10 += (double)p[(dy+1)*4 + dx]   * w;
            d11 += (double)p[(dy+1)*4 + dx+1] * w;
          }
        double thd = thrD[o];
        bit = (d00 >= thd) || (d01 >= thd) || (d10 >= thd) || (d11 >= thd);
      } else {
        bit = (mx >= th);
      }
      bits |= (u32)bit << o;
    }
    hp[(pi+2)*18 + (pj+2)] = (u16)bits;
  }
  __syncthreads();

  // ---- branches: gather 5x5 taps from zero-padded tile
  if (t < 196) {
    const u16* hpb = &hp[pi*18 + pj];
    u32 tp[25];
    #pragma unroll
    for (int r = 0; r < 5; r++)
      #pragma unroll
      for (int c = 0; c < 5; c++) tp[r*5+c] = hpb[r*18 + c];
    u32 h0 = tp[12];
    u64 qc[6], qb[2];
    u32 qc6 = tp[24], qb2 = tp[18];
    qc[0] = (u64)tp[0]  | (u64)tp[1]<<16  | (u64)tp[2]<<32  | (u64)tp[3]<<48;
    qc[1] = (u64)tp[4]  | (u64)tp[5]<<16  | (u64)tp[6]<<32  | (u64)tp[7]<<48;
    qc[2] = (u64)tp[8]  | (u64)tp[9]<<16  | (u64)tp[10]<<32 | (u64)tp[11]<<48;
    qc[3] = (u64)tp[12] | (u64)tp[13]<<16 | (u64)tp[14]<<32 | (u64)tp[15]<<48;
    qc[4] = (u64)tp[16] | (u64)tp[17]<<16 | (u64)tp[18]<<32 | (u64)tp[19]<<48;
    qc[5] = (u64)tp[20] | (u64)tp[21]<<16 | (u64)tp[22]<<32 | (u64)tp[23]<<48;
    qb[0] = (u64)tp[6]  | (u64)tp[7]<<16  | (u64)tp[8]<<32  | (u64)tp[11]<<48;
    qb[1] = (u64)tp[12] | (u64)tp[13]<<16 | (u64)tp[16]<<32 | (u64)tp[17]<<48;
    int rc = (pi < 2) ? pi : (pi > 11 ? pi - 9 : 2);
    int cc = (pj < 2) ? pj : (pj > 11 ? pj - 9 : 2);
    const u64* mrow = &smbc[(rc*5 + cc)*33];
    const ulonglong2* R2 = (const ulonglong2*)wrecL;
    u32 r0 = 0, r1 = 0, r2 = 0;
    #pragma unroll 8
    for (int ch = 0; ch < 32; ch++) {
      ulonglong2 w01 = R2[ch*6+0], w23 = R2[ch*6+1], w45 = R2[ch*6+2];
      ulonglong2 w67 = R2[ch*6+3], w89 = R2[ch*6+4];
      u64 meta = mrow[ch];
      int Sc = __popcll(qc[0]^w01.x) + __popcll(qc[1]^w01.y) + __popcll(qc[2]^w23.x)
             + __popcll(qc[3]^w23.y) + __popcll(qc[4]^w45.x) + __popcll(qc[5]^w45.y)
             + __popc(qc6 ^ (u32)w67.x);
      int Sb = __popcll(qb[0]^w67.y) + __popcll(qb[1]^w89.x) + __popc(qb2 ^ (u32)w89.y);
      int Sa = __popc(h0 ^ (u32)(meta >> 48));
      r0 |= (u32)(Sa < (int)((meta >> 32) & 0xFFFFu)) << ch;
      r1 |= (u32)(Sb < (int)((meta >> 16) & 0xFFFFu)) << ch;
      r2 |= (u32)(Sc < (int)(meta & 0xFFFFu)) << ch;
    }
    rr[t][0] = r0; rr[t][1] = r1; rr[t][2] = r2;
  }
  __syncthreads();
  // pool 2x2 (OR) and store directly: 148 u32, f' = s*96 + c order
  if (t < 148) {
    u32 v = 0;
    if (t < 147) {
      int s = t / 3, qq = t - 3*s;
      int sp = s / 7, sj = s - 7*sp;
      int base = (2*sp)*14 + 2*sj;
      v = rr[base][qq] | rr[base+1][qq] | rr[base+14][qq] | rr[base+15][qq];
    }
    h2u32[(size_t)b*148 + t] = v;
  }
}

// ---------------------------------------------------------------- C: FC1 XNOR-GEMM (64img x 64out, 16 dots/thread)
// wL rows permuted: row o stored at perm(o)=(o&15)*4+(o>>4) so each thread's 4 W-rows are
// 592B apart -> distinct bank groups (conflict-free); A-rows pair 2-way (free).
__global__ __launch_bounds__(256) void kfc1(const u64* __restrict__ h2, const u64* __restrict__ wf1p,
                                            const int* __restrict__ smf1, u64* __restrict__ hb2) {
  __shared__ __align__(16) u64 aL[64*74];
  __shared__ __align__(16) u64 wL[64*74];
  __shared__ unsigned char bitsb[64][64];
  int bx = blockIdx.x, by = blockIdx.y, t = threadIdx.x;
  const ulonglong2* ga = reinterpret_cast<const ulonglong2*>(h2 + (size_t)by*(64*74));
  ulonglong2* la = reinterpret_cast<ulonglong2*>(aL);
  for (int i = t; i < 64*37; i += 256) la[i] = ga[i];
  const ulonglong2* gw = reinterpret_cast<const ulonglong2*>(wf1p + (size_t)bx*(64*74));
  ulonglong2* lw = reinterpret_cast<ulonglong2*>(wL);
  for (int i = t; i < 64*37; i += 256) {
    int o = i / 37, w2 = i - 37*o;
    int po = ((o & 15) << 2) | (o >> 4);
    lw[po*37 + w2] = gw[i];
  }
  __syncthreads();
  int ig = t & 15, og = t >> 4;        // imgs ig+16k, outs og+16k (k=0..3)
  const ulonglong2* A0 = reinterpret_cast<const ulonglong2*>(aL + (ig     )*74);
  const ulonglong2* A1 = reinterpret_cast<const ulonglong2*>(aL + (ig + 16)*74);
  const ulonglong2* A2 = reinterpret_cast<const ulonglong2*>(aL + (ig + 32)*74);
  const ulonglong2* A3 = reinterpret_cast<const ulonglong2*>(aL + (ig + 48)*74);
  const ulonglong2* W0 = reinterpret_cast<const ulonglong2*>(wL + (og*4 + 0)*74);
  const ulonglong2* W1 = reinterpret_cast<const ulonglong2*>(wL + (og*4 + 1)*74);
  const ulonglong2* W2 = reinterpret_cast<const ulonglong2*>(wL + (og*4 + 2)*74);
  const ulonglong2* W3 = reinterpret_cast<const ulonglong2*>(wL + (og*4 + 3)*74);
  int s[4][4];
  #pragma unroll
  for (int i = 0; i < 4; i++)
    #pragma unroll
    for (int j = 0; j < 4; j++) s[i][j] = 0;
  for (int w = 0; w < 37; w++) {
    ulonglong2 b0 = W0[w], b1 = W1[w], b2 = W2[w], b3 = W3[w];
    ulonglong2 a;
    a = A0[w];
    s[0][0] += __popcll(a.x^b0.x)+__popcll(a.y^b0.y); s[0][1] += __popcll(a.x^b1.x)+__popcll(a.y^b1.y);
    s[0][2] += __popcll(a.x^b2.x)+__popcll(a.y^b2.y); s[0][3] += __popcll(a.x^b3.x)+__popcll(a.y^b3.y);
    a = A1[w];
    s[1][0] += __popcll(a.x^b0.x)+__popcll(a.y^b0.y); s[1][1] += __popcll(a.x^b1.x)+__popcll(a.y^b1.y);
    s[1][2] += __popcll(a.x^b2.x)+__popcll(a.y^b2.y); s[1][3] += __popcll(a.x^b3.x)+__popcll(a.y^b3.y);
    a = A2[w];
    s[2][0] += __popcll(a.x^b0.x)+__popcll(a.y^b0.y); s[2][1] += __popcll(a.x^b1.x)+__popcll(a.y^b1.y);
    s[2][2] += __popcll(a.x^b2.x)+__popcll(a.y^b2.y); s[2][3] += __popcll(a.x^b3.x)+__popcll(a.y^b3.y);
    a = A3[w];
    s[3][0] += __popcll(a.x^b0.x)+__popcll(a.y^b0.y); s[3][1] += __popcll(a.x^b1.x)+__popcll(a.y^b1.y);
    s[3][2] += __popcll(a.x^b2.x)+__popcll(a.y^b2.y); s[3][3] += __popcll(a.x^b3.x)+__popcll(a.y^b3.y);
  }
  int th0 = smf1[bx*64 + og];
  int th1 = smf1[bx*64 + og + 16];
  int th2 = smf1[bx*64 + og + 32];
  int th3 = smf1[bx*64 + og + 48];
  #pragma unroll
  for (int i = 0; i < 4; i++) {
    int im = ig + 16*i;
    bitsb[im][og     ] = s[i][0] < th0;
    bitsb[im][og + 16] = s[i][1] < th1;
    bitsb[im][og + 32] = s[i][2] < th2;
    bitsb[im][og + 48] = s[i][3] < th3;
  }
  __syncthreads();
  if (t < 64) {
    u64 wd = 0;
    #pragma unroll
    for (int j = 0; j < 64; j++) wd |= (u64)bitsb[t][j] << j;
    hb2[(size_t)(by*64 + t)*16 + bx] = wd;
  }
}

// ---------------------------------------------------------------- D: FC2 + BN + log_softmax
__global__ __launch_bounds__(256) void kfc2(const u64* __restrict__ hb2, const char* __restrict__ ws,
                                            float* __restrict__ out, int B) {
  __shared__ u64 w2[160];
  __shared__ float a2s[10], c2s[10];
  const u64* wf2p = (const u64*)(ws + OFF_WF2P);
  const float* a2 = (const float*)(ws + OFF_A2);
  const float* c2 = (const float*)(ws + OFF_C2);
  int t = threadIdx.x;
  for (int i = t; i < 160; i += 256) w2[i] = wf2p[i];
  if (t < 10) { a2s[t] = a2[t]; c2s[t] = c2[t]; }
  __syncthreads();
  int img = blockIdx.x*256 + t;
  if (img >= B) return;
  u64 a[16];
  #pragma unroll
  for (int w = 0; w < 16; w++) a[w] = hb2[(size_t)img*16 + w];
  float z[10];
  #pragma unroll
  for (int o = 0; o < 10; o++) {
    int S = 0;
    #pragma unroll
    for (int w = 0; w < 16; w++) S += __popcll(a[w] ^ w2[o*16 + w]);
    z[o] = (float)(1024 - 2*S) * a2s[o] + c2s[o];
  }
  float M = z[0];
  #pragma unroll
  for (int o = 1; o < 10; o++) M = fmaxf(M, z[o]);
  float se = 0.f;
  #pragma unroll
  for (int o = 0; o < 10; o++) se += expf(z[o] - M);
  float lse = M + logf(se);
  #pragma unroll
  for (int o = 0; o < 10; o++) out[(size_t)img*10 + o] = z[o] - lse;
}

// ----------------------------------------------------------------
extern "C" void kernel_launch(void* const* d_in, const int* in_sizes, int n_in,
                              void* d_out, int out_size, void* d_ws, size_t ws_size,
                              hipStream_t stream) {
  int B = in_sizes[0] / 784;   // 4096
  char* ws = (char*)d_ws;
  InPtrs P;
  for (int i = 0; i < 37; i++) P.p[i] = (const float*)d_in[i];

  kprep<<<4, 1024, 0, stream>>>(P, ws);
  kfused<<<1024 + B, 256, 0, stream>>>((const float*)d_in[0], (const float*)d_in[25], ws,
                                       (u32*)(ws + OFF_H2), (u64*)(ws + OFF_WF1P));
  dim3 g(16, B/64);
  kfc1<<<g, 256, 0, stream>>>((const u64*)(ws + OFF_H2), (const u64*)(ws + OFF_WF1P),
                              (const int*)(ws + OFF_SMAXF1), (u64*)(ws + OFF_HB2));
  kfc2<<<(B + 255)/256, 256, 0, stream>>>((const u64*)(ws + OFF_HB2), ws, (float*)d_out, B);
}